// Round 8
// baseline (373.618 us; speedup 1.0000x reference)
//
#include <hip/hip_runtime.h>
#include <hip/hip_bf16.h>
#include <math.h>

#define DEV __device__ __forceinline__

typedef __attribute__((ext_vector_type(4))) float f32x4;
typedef __attribute__((ext_vector_type(16))) float f32x16;
typedef __attribute__((ext_vector_type(8))) short bf16x8;
typedef __attribute__((ext_vector_type(4))) unsigned short us4;

// ---------- scalar helpers ----------
DEV unsigned short f2bf(float f) {
    union { float f; unsigned u; } v; v.f = f;
    unsigned r = v.u + 0x7FFF + ((v.u >> 16) & 1);
    return (unsigned short)(r >> 16);
}

DEV float bf2f(unsigned short u) {
    union { unsigned u; float f; } v; v.u = (unsigned)u << 16; return v.f;
}

DEV void async16(const void* g, void* l) {
    __builtin_amdgcn_global_load_lds(
        (const __attribute__((address_space(1))) void*)g,
        (__attribute__((address_space(3))) void*)l, 16, 0, 0);
}

// bijective XCD-aware remap (m204): chunked so consecutive wgids share an XCD's L2
DEV int xcd_swizzle(int flat, int nwg) {
    int q = nwg >> 3, r8 = nwg & 7;
    int xcd = flat & 7, idx = flat >> 3;
    return (xcd < r8 ? xcd * (q + 1) : r8 * (q + 1) + (xcd - r8) * q) + idx;
}

// ---------- f32 -> bf16 convert ----------
__global__ void cvt_kernel(const float* __restrict__ in, unsigned short* __restrict__ out, int n4) {
    int i = blockIdx.x * blockDim.x + threadIdx.x;
    if (i >= n4) return;
    f32x4 v = ((const f32x4*)in)[i];
    us4 o;
    o.x = f2bf(v.x); o.y = f2bf(v.y); o.z = f2bf(v.z); o.w = f2bf(v.w);
    ((us4*)out)[i] = o;
}

// ---------- GEMM 128x128 (m97 structure): C[M,N] = A[M,K] * B[N,K]^T ----------
// EPI: 0 = bf16 out, 1 = f32 out, 2 = +bias, exact GELU, bf16 out, 3 = +bias, f32 out
#define BM 128
#define BN 128
#define BKK 64

template<int EPI>
__global__ __launch_bounds__(256) void gemm_bt(
    const unsigned short* __restrict__ A,
    const unsigned short* __restrict__ B,
    float* __restrict__ Cf, unsigned short* __restrict__ Cb,
    const float* __restrict__ bias,
    int M, int N, int K)
{
    __shared__ unsigned short As[BM * BKK];
    __shared__ unsigned short Bs[BN * BKK];

    const int tid  = threadIdx.x;
    const int wid  = tid >> 6, lane = tid & 63;
    const int l15  = lane & 15, l16 = lane >> 4;
    const int wr   = wid >> 1, wc = wid & 1;

    const int nwg  = gridDim.x * gridDim.y;
    const int flat = xcd_swizzle(blockIdx.y * gridDim.x + blockIdx.x, nwg);
    const int row0 = (flat / gridDim.x) * BM;
    const int col0 = (flat % gridDim.x) * BN;

    f32x4 acc[4][4] = {};

    const int nkt = K / BKK;
    for (int kt = 0; kt < nkt; ++kt) {
        const int k0 = kt * BKK;
        __syncthreads();
        // stage A and B tiles: linear LDS dest, inverse-swizzled global source (rule 21)
#pragma unroll
        for (int i = 0; i < 4; ++i) {
            int c = i * 256 + tid;          // chunk index, 16B per chunk
            int row = c >> 3, slot = c & 7;
            int ks = (slot ^ (row & 7)) * 8;
            async16(A + (size_t)(row0 + row) * K + k0 + ks, (char*)As + c * 16);
            async16(B + (size_t)(col0 + row) * K + k0 + ks, (char*)Bs + c * 16);
        }
        __syncthreads();   // compiler drains vmcnt before barrier
#pragma unroll
        for (int kk = 0; kk < 2; ++kk) {
            bf16x8 af[4], bfr[4];
#pragma unroll
            for (int m = 0; m < 4; ++m) {
                int r = wr * 64 + m * 16 + l15;
                int slot = (kk * 4 + l16) ^ (r & 7);
                af[m] = *(const bf16x8*)((const char*)As + r * 128 + slot * 16);
            }
#pragma unroll
            for (int n = 0; n < 4; ++n) {
                int r = wc * 64 + n * 16 + l15;
                int slot = (kk * 4 + l16) ^ (r & 7);
                bfr[n] = *(const bf16x8*)((const char*)Bs + r * 128 + slot * 16);
            }
#pragma unroll
            for (int m = 0; m < 4; ++m)
#pragma unroll
                for (int n = 0; n < 4; ++n)
                    acc[m][n] = __builtin_amdgcn_mfma_f32_16x16x32_bf16(af[m], bfr[n], acc[m][n], 0, 0, 0);
        }
    }

    // epilogue: C/D layout col=lane&15, row=(lane>>4)*4+reg  [m89/m91]
#pragma unroll
    for (int m = 0; m < 4; ++m) {
        int grow = row0 + wr * 64 + m * 16 + l16 * 4;
#pragma unroll
        for (int n = 0; n < 4; ++n) {
            int gcol = col0 + wc * 64 + n * 16 + l15;
            float bv = (EPI >= 2) ? bias[gcol] : 0.f;
#pragma unroll
            for (int r = 0; r < 4; ++r) {
                float v = acc[m][n][r];
                size_t idx = (size_t)(grow + r) * N + gcol;
                if (EPI == 0) {
                    Cb[idx] = f2bf(v);
                } else if (EPI == 1) {
                    Cf[idx] = v;
                } else if (EPI == 2) {
                    v += bv;
                    v = 0.5f * v * (1.f + erff(v * 0.70710678118f));
                    Cb[idx] = f2bf(v);
                } else {
                    Cf[idx] = v + bv;
                }
            }
        }
    }
}

// ---------- split-K GEMM 128x128: P[s][M][N] = A[:, s*Klen:(s+1)*Klen] * B^T ----------
// blockIdx.z = split s. Partials bf16; summed (plus optional bias) in ln_sum_kernel.
__global__ __launch_bounds__(256) void gemm_splitk(
    const unsigned short* __restrict__ A,
    const unsigned short* __restrict__ B,
    unsigned short* __restrict__ Pb,
    int N, int Kld, int Klen)
{
    __shared__ unsigned short As[BM * BKK];
    __shared__ unsigned short Bs[BN * BKK];

    const int tid  = threadIdx.x;
    const int wid  = tid >> 6, lane = tid & 63;
    const int l15  = lane & 15, l16 = lane >> 4;
    const int wr   = wid >> 1, wc = wid & 1;

    const int s = blockIdx.z;
    const unsigned short* Ab = A + (size_t)s * Klen;
    const unsigned short* Bb = B + (size_t)s * Klen;

    const int nwg  = gridDim.x * gridDim.y;
    const int flat = xcd_swizzle(blockIdx.y * gridDim.x + blockIdx.x, nwg);
    const int row0 = (flat / gridDim.x) * BM;
    const int col0 = (flat % gridDim.x) * BN;

    f32x4 acc[4][4] = {};

    const int nkt = Klen / BKK;
    for (int kt = 0; kt < nkt; ++kt) {
        const int k0 = kt * BKK;
        __syncthreads();
#pragma unroll
        for (int i = 0; i < 4; ++i) {
            int c = i * 256 + tid;
            int row = c >> 3, slot = c & 7;
            int ks = (slot ^ (row & 7)) * 8;
            async16(Ab + (size_t)(row0 + row) * Kld + k0 + ks, (char*)As + c * 16);
            async16(Bb + (size_t)(col0 + row) * Kld + k0 + ks, (char*)Bs + c * 16);
        }
        __syncthreads();
#pragma unroll
        for (int kk = 0; kk < 2; ++kk) {
            bf16x8 af[4], bfr[4];
#pragma unroll
            for (int m = 0; m < 4; ++m) {
                int r = wr * 64 + m * 16 + l15;
                int slot = (kk * 4 + l16) ^ (r & 7);
                af[m] = *(const bf16x8*)((const char*)As + r * 128 + slot * 16);
            }
#pragma unroll
            for (int n = 0; n < 4; ++n) {
                int r = wc * 64 + n * 16 + l15;
                int slot = (kk * 4 + l16) ^ (r & 7);
                bfr[n] = *(const bf16x8*)((const char*)Bs + r * 128 + slot * 16);
            }
#pragma unroll
            for (int m = 0; m < 4; ++m)
#pragma unroll
                for (int n = 0; n < 4; ++n)
                    acc[m][n] = __builtin_amdgcn_mfma_f32_16x16x32_bf16(af[m], bfr[n], acc[m][n], 0, 0, 0);
        }
    }

    unsigned short* P = Pb + (size_t)s * (size_t)(gridDim.y * BM) * N;
#pragma unroll
    for (int m = 0; m < 4; ++m) {
        int grow = row0 + wr * 64 + m * 16 + l16 * 4;
#pragma unroll
        for (int n = 0; n < 4; ++n) {
            int gcol = col0 + wc * 64 + n * 16 + l15;
#pragma unroll
            for (int r = 0; r < 4; ++r)
                P[(size_t)(grow + r) * N + gcol] = f2bf(acc[m][n][r]);
        }
    }
}

// ---------- GEMM 256x256, 8 waves, double-buffered with COUNTED vmcnt (T4/m218) ----------
// Raw s_barrier + s_waitcnt vmcnt(8): next tile's 8 loads/thread stay in flight
// across the whole compute phase; only the current tile's loads are waited on.
template<int EPI>
__global__ __launch_bounds__(512, 2) void gemm256(
    const unsigned short* __restrict__ A,
    const unsigned short* __restrict__ B,
    float* __restrict__ Cf, unsigned short* __restrict__ Cb,
    const float* __restrict__ bias,
    int M, int N, int K)
{
    __shared__ unsigned short As[2][256 * 64];   // 32 KB x2
    __shared__ unsigned short Bs[2][256 * 64];   // 32 KB x2  -> 128 KB total

    const int tid = threadIdx.x;
    const int wid = tid >> 6, lane = tid & 63;
    const int l15 = lane & 15, l16 = lane >> 4;
    const int wr = wid >> 2, wc = wid & 3;       // 2 (M) x 4 (N) waves, each 128x64

    const int nwg  = gridDim.x * gridDim.y;
    const int flat = xcd_swizzle(blockIdx.y * gridDim.x + blockIdx.x, nwg);
    const int row0 = (flat / gridDim.x) * 256;
    const int col0 = (flat % gridDim.x) * 256;

    f32x4 acc[8][4] = {};

    auto stage = [&](int buf, int k0) {          // 8 global_load_lds per thread
#pragma unroll
        for (int i = 0; i < 4; ++i) {
            int c = i * 512 + tid;               // 2048 chunks of 16B per matrix
            int row = c >> 3, slot = c & 7;
            int ks = (slot ^ (row & 7)) * 8;
            async16(A + (size_t)(row0 + row) * K + k0 + ks, (char*)As[buf] + c * 16);
            async16(B + (size_t)(col0 + row) * K + k0 + ks, (char*)Bs[buf] + c * 16);
        }
    };

    stage(0, 0);
    int cur = 0;
    const int nkt = K / 64;
    for (int kt = 0; kt < nkt; ++kt) {
        if (kt + 1 < nkt) {
            stage(cur ^ 1, (kt + 1) * 64);       // issue next tile FIRST
            __builtin_amdgcn_sched_barrier(0);
            asm volatile("s_waitcnt vmcnt(8)" ::: "memory");   // current tile's 8 done; next 8 fly
        } else {
            __builtin_amdgcn_sched_barrier(0);
            asm volatile("s_waitcnt vmcnt(0)" ::: "memory");   // last tile: full drain
        }
        __builtin_amdgcn_sched_barrier(0);
        __builtin_amdgcn_s_barrier();            // publish buf[cur]
        __builtin_amdgcn_sched_barrier(0);
#pragma unroll
        for (int kk = 0; kk < 2; ++kk) {
            bf16x8 af[8], bfr[4];
#pragma unroll
            for (int m = 0; m < 8; ++m) {
                int r = wr * 128 + m * 16 + l15;
                int slot = (kk * 4 + l16) ^ (r & 7);
                af[m] = *(const bf16x8*)((const char*)As[cur] + r * 128 + slot * 16);
            }
#pragma unroll
            for (int n = 0; n < 4; ++n) {
                int r = wc * 64 + n * 16 + l15;
                int slot = (kk * 4 + l16) ^ (r & 7);
                bfr[n] = *(const bf16x8*)((const char*)Bs[cur] + r * 128 + slot * 16);
            }
            __builtin_amdgcn_s_setprio(1);
#pragma unroll
            for (int m = 0; m < 8; ++m)
#pragma unroll
                for (int n = 0; n < 4; ++n)
                    acc[m][n] = __builtin_amdgcn_mfma_f32_16x16x32_bf16(af[m], bfr[n], acc[m][n], 0, 0, 0);
            __builtin_amdgcn_s_setprio(0);
        }
        __builtin_amdgcn_sched_barrier(0);
        __builtin_amdgcn_s_barrier();            // all waves done reading buf[cur]
        __builtin_amdgcn_sched_barrier(0);       // before next iter overwrites it
        cur ^= 1;
    }

#pragma unroll
    for (int m = 0; m < 8; ++m) {
        int grow = row0 + wr * 128 + m * 16 + l16 * 4;
#pragma unroll
        for (int n = 0; n < 4; ++n) {
            int gcol = col0 + wc * 64 + n * 16 + l15;
            float bv = (EPI >= 2) ? bias[gcol] : 0.f;
#pragma unroll
            for (int r = 0; r < 4; ++r) {
                float v = acc[m][n][r];
                size_t idx = (size_t)(grow + r) * N + gcol;
                if (EPI == 0) {
                    Cb[idx] = f2bf(v);
                } else if (EPI == 1) {
                    Cf[idx] = v;
                } else if (EPI == 2) {
                    v += bv;
                    v = 0.5f * v * (1.f + erff(v * 0.70710678118f));
                    Cb[idx] = f2bf(v);
                } else {
                    Cf[idx] = v + bv;
                }
            }
        }
    }
}

// ---------- V transpose: qkv V-part [B,N,H,64] -> vt [B,H,64,N] ----------
__global__ __launch_bounds__(256) void transpose_v(const unsigned short* __restrict__ qkv,
                                                   unsigned short* __restrict__ vt)
{
    __shared__ unsigned short t[64][72];
    const int n0 = blockIdx.x * 64;
    const int bh = blockIdx.y;
    const int b = bh >> 4, h = bh & 15;
    const int tid = threadIdx.x;
#pragma unroll
    for (int i = 0; i < 2; ++i) {
        int c = i * 256 + tid;
        int row = c >> 3, col0 = (c & 7) * 8;
        const unsigned short* src = qkv + (size_t)(b * 1024 + n0 + row) * 3072 + 2048 + h * 64 + col0;
        bf16x8 v = *(const bf16x8*)src;
#pragma unroll
        for (int j = 0; j < 8; ++j) t[row][col0 + j] = (unsigned short)v[j];
    }
    __syncthreads();
#pragma unroll
    for (int i = 0; i < 2; ++i) {
        int c = i * 256 + tid;
        int hd = c >> 3, col0 = (c & 7) * 8;
        bf16x8 v;
#pragma unroll
        for (int j = 0; j < 8; ++j) v[j] = (short)t[col0 + j][hd];
        *(bf16x8*)(vt + ((size_t)bh * 64 + hd) * 1024 + n0 + col0) = v;
    }
}

// ---------- fused attention: swapped QK^T (S^T), 32x32 MFMA, in-register softmax ----------
// Wave owns 32 q rows (q = lane&31). Block = 4 waves = 128 q. Grid: (1024/128, B*H).
__global__ __launch_bounds__(256) void attn_kernel(const unsigned short* __restrict__ qkv,
                                                   const int* __restrict__ coords,
                                                   const unsigned short* __restrict__ vt,
                                                   unsigned short* __restrict__ out)
{
    __shared__ unsigned short Ks[2][64 * 64];   // K tile, rows = kv, swizzled
    __shared__ unsigned short Vs[2][64 * 64];   // V^T tile, rows = d, swizzled
    __shared__ float cF[1024 * 2];              // slope2-scaled coords for this b

    const int tid = threadIdx.x, wid = tid >> 6, lane = tid & 63;
    const int l31 = lane & 31, hi = lane >> 5;
    const int q0 = blockIdx.x * 128;
    const int bh = blockIdx.y;
    const int b = bh >> 4, h = bh & 15;
    const float LOG2E = 1.4426950408889634f;
    const float slope2 = exp2f(-0.5f * (float)(h + 1)) * LOG2E;
    const float scale2 = 0.125f * LOG2E;

    // staging descriptors (rule 21: linear LDS dest, inverse-swizzled global src)
    const int c0 = tid,       r0c = c0 >> 3, ks0 = ((c0 & 7) ^ (r0c & 7)) * 8;
    const int c1 = 256 + tid, r1c = c1 >> 3, ks1 = ((c1 & 7) ^ (r1c & 7)) * 8;
    const unsigned short* kbase = qkv + (size_t)(b * 1024) * 3072 + 1024 + h * 64;
    const unsigned short* vbase = vt + (size_t)bh * 64 * 1024;

    // pre-scale coords into LDS (bias = |qxs-kxs| + |qys-kys|, log2 domain)
    {
        const int2* cp = (const int2*)coords + b * 1024;
#pragma unroll
        for (int i = 0; i < 4; ++i) {
            int kv = i * 256 + tid;
            int2 c = cp[kv];
            cF[kv * 2]     = slope2 * (float)c.x;
            cF[kv * 2 + 1] = slope2 * (float)c.y;
        }
    }

    const int qrow = q0 + wid * 32 + l31;
    // Q as B-fragment: row=q (lane&31), k = c16*16 + hi*8 + j
    bf16x8 qf[4];
    {
        const unsigned short* qp = qkv + (size_t)(b * 1024 + qrow) * 3072 + h * 64 + hi * 8;
        qf[0] = *(const bf16x8*)qp;
        qf[1] = *(const bf16x8*)(qp + 16);
        qf[2] = *(const bf16x8*)(qp + 32);
        qf[3] = *(const bf16x8*)(qp + 48);
    }
    float qxs, qys;
    {
        int2 qc = ((const int2*)coords)[b * 1024 + qrow];
        qxs = slope2 * (float)qc.x; qys = slope2 * (float)qc.y;
    }

    float mr = -1e30f, lr = 0.f;
    f32x16 o0 = (f32x16)0.f, o1 = (f32x16)0.f;   // O^T tiles: d 0-31, 32-63

    // prologue: stage tile 0
    async16(kbase + (size_t)r0c * 3072 + ks0, (char*)Ks[0] + c0 * 16);
    async16(kbase + (size_t)r1c * 3072 + ks1, (char*)Ks[0] + c1 * 16);
    async16(vbase + (size_t)r0c * 1024 + ks0, (char*)Vs[0] + c0 * 16);
    async16(vbase + (size_t)r1c * 1024 + ks1, (char*)Vs[0] + c1 * 16);
    int cur = 0;

    for (int t = 0; t < 16; ++t) {
        const int kv0 = t * 64;
        __syncthreads();                    // drains vmcnt + coord writes
        if (t < 15) {                       // prefetch next tile under compute
            const int kv1 = kv0 + 64;
            async16(kbase + (size_t)(kv1 + r0c) * 3072 + ks0, (char*)Ks[cur ^ 1] + c0 * 16);
            async16(kbase + (size_t)(kv1 + r1c) * 3072 + ks1, (char*)Ks[cur ^ 1] + c1 * 16);
            async16(vbase + (size_t)r0c * 1024 + kv1 + ks0, (char*)Vs[cur ^ 1] + c0 * 16);
            async16(vbase + (size_t)r1c * 1024 + kv1 + ks1, (char*)Vs[cur ^ 1] + c1 * 16);
        }

        // S^T[kv][q] = K·Q^T : A = K (rows kv), B = Q (rows q)
        f32x16 s0 = (f32x16)0.f, s1 = (f32x16)0.f;
        __builtin_amdgcn_s_setprio(1);
#pragma unroll
        for (int c16 = 0; c16 < 4; ++c16) {
            int slot = ((c16 * 2 + hi) ^ (l31 & 7)) * 16;
            bf16x8 k0f = *(const bf16x8*)((const char*)Ks[cur] + l31 * 128 + slot);
            bf16x8 k1f = *(const bf16x8*)((const char*)Ks[cur] + (32 + l31) * 128 + slot);
            s0 = __builtin_amdgcn_mfma_f32_32x32x16_bf16(k0f, qf[c16], s0, 0, 0, 0);
            s1 = __builtin_amdgcn_mfma_f32_32x32x16_bf16(k1f, qf[c16], s1, 0, 0, 0);
        }
        __builtin_amdgcn_s_setprio(0);

        // bias: s_log2 = s*scale2 + |qxs-kxs| + |qys-kys|
        // lane's kv rows: (r&3) + 8*(r>>2) + 4*hi + 32*T   [m74/m101 C layout]
#pragma unroll
        for (int T = 0; T < 2; ++T) {
            f32x16& S = T ? s1 : s0;
#pragma unroll
            for (int u = 0; u < 4; ++u) {
                int kvb = kv0 + T * 32 + u * 8 + hi * 4;
                f32x4 ca = *(const f32x4*)&cF[kvb * 2];
                f32x4 cb = *(const f32x4*)&cF[kvb * 2 + 4];
                S[4*u+0] = S[4*u+0] * scale2 + (fabsf(qxs - ca.x) + fabsf(qys - ca.y));
                S[4*u+1] = S[4*u+1] * scale2 + (fabsf(qxs - ca.z) + fabsf(qys - ca.w));
                S[4*u+2] = S[4*u+2] * scale2 + (fabsf(qxs - cb.x) + fabsf(qys - cb.y));
                S[4*u+3] = S[4*u+3] * scale2 + (fabsf(qxs - cb.z) + fabsf(qys - cb.w));
            }
        }

        // online softmax (per-lane q row): in-lane max + one cross-half shfl
        float pm = s0[0];
#pragma unroll
        for (int i = 1; i < 16; ++i) pm = fmaxf(pm, s0[i]);
#pragma unroll
        for (int i = 0; i < 16; ++i) pm = fmaxf(pm, s1[i]);
        pm = fmaxf(pm, __shfl_xor(pm, 32, 64));
        if (__any(pm > mr + 8.0f)) {        // defer-max (T13): rescale only on real growth
            float mn = fmaxf(mr, pm);
            float corr = exp2f(mr - mn);
            mr = mn;
            lr *= corr;
#pragma unroll
            for (int i = 0; i < 16; ++i) { o0[i] *= corr; o1[i] *= corr; }
        }
        float sum = 0.f;
#pragma unroll
        for (int i = 0; i < 16; ++i) { float p = exp2f(s0[i] - mr); s0[i] = p; sum += p; }
#pragma unroll
        for (int i = 0; i < 16; ++i) { float p = exp2f(s1[i] - mr); s1[i] = p; sum += p; }
        sum += __shfl_xor(sum, 32, 64);
        lr += sum;

        // P -> bf16 B-fragments via cvt_pk + permlane32_swap (T12)
        bf16x8 pf[4];
#pragma unroll
        for (int c = 0; c < 4; ++c) {
            const f32x16& S = (c < 2) ? s0 : s1;
            const int e = (c & 1) * 8;
            unsigned x0, x1, y0, y1;
            asm("v_cvt_pk_bf16_f32 %0, %1, %2" : "=v"(x0) : "v"(S[e+0]), "v"(S[e+1]));
            asm("v_cvt_pk_bf16_f32 %0, %1, %2" : "=v"(x1) : "v"(S[e+2]), "v"(S[e+3]));
            asm("v_cvt_pk_bf16_f32 %0, %1, %2" : "=v"(y0) : "v"(S[e+4]), "v"(S[e+5]));
            asm("v_cvt_pk_bf16_f32 %0, %1, %2" : "=v"(y1) : "v"(S[e+6]), "v"(S[e+7]));
            asm("v_permlane32_swap_b32 %0, %1" : "+v"(x0), "+v"(y0));
            asm("v_permlane32_swap_b32 %0, %1" : "+v"(x1), "+v"(y1));
            union { unsigned u[4]; bf16x8 v; } pk_;
            pk_.u[0] = x0; pk_.u[1] = x1; pk_.u[2] = y0; pk_.u[3] = y1;
            pf[c] = pk_.v;
        }

        // O^T += V^T · P : A = V^T (rows d), B = P (rows q)
        __builtin_amdgcn_s_setprio(1);
#pragma unroll
        for (int c = 0; c < 4; ++c) {
            int slot = ((c * 2 + hi) ^ (l31 & 7)) * 16;
            bf16x8 v0 = *(const bf16x8*)((const char*)Vs[cur] + l31 * 128 + slot);
            bf16x8 v1 = *(const bf16x8*)((const char*)Vs[cur] + (32 + l31) * 128 + slot);
            o0 = __builtin_amdgcn_mfma_f32_32x32x16_bf16(v0, pf[c], o0, 0, 0, 0);
            o1 = __builtin_amdgcn_mfma_f32_32x32x16_bf16(v1, pf[c], o1, 0, 0, 0);
        }
        __builtin_amdgcn_s_setprio(0);
        cur ^= 1;
    }

    const float inv = 1.0f / lr;
    unsigned short* op = out + (size_t)(b * 1024 + qrow) * 1024 + h * 64;
#pragma unroll
    for (int Td = 0; Td < 2; ++Td) {
        const f32x16& O = Td ? o1 : o0;
#pragma unroll
        for (int u = 0; u < 4; ++u) {
            us4 w;
            w.x = f2bf(O[4*u+0] * inv);
            w.y = f2bf(O[4*u+1] * inv);
            w.z = f2bf(O[4*u+2] * inv);
            w.w = f2bf(O[4*u+3] * inv);
            *(us4*)(op + Td * 32 + u * 8 + hi * 4) = w;
        }
    }
}

// ---------- LayerNorm(a + sum_{s<nsplit} P[s] + bias?) -> f32 out (opt) + bf16 out (opt) ----------
__global__ __launch_bounds__(256) void ln_sum_kernel(const float* __restrict__ a,
                                                     const unsigned short* __restrict__ pb, int nsplit,
                                                     const float* __restrict__ bias,
                                                     const float* __restrict__ g, const float* __restrict__ be,
                                                     float* __restrict__ xout, unsigned short* __restrict__ xb)
{
    __shared__ float red[2][4];
    const int row = blockIdx.x, tid = threadIdx.x;
    const int wid = tid >> 6, lane = tid & 63;
    const size_t idx = (size_t)row * 256 + tid;
    f32x4 v = ((const f32x4*)a)[idx];
    for (int s = 0; s < nsplit; ++s) {
        us4 p = ((const us4*)pb)[(size_t)s * 1048576 + idx];   // stride = 4096*1024/4 us4
        v.x += bf2f(p.x); v.y += bf2f(p.y); v.z += bf2f(p.z); v.w += bf2f(p.w);
    }
    if (bias) {
        f32x4 bv = ((const f32x4*)bias)[tid];
        v.x += bv.x; v.y += bv.y; v.z += bv.z; v.w += bv.w;
    }
    float s1 = v.x + v.y + v.z + v.w;
    float s2 = v.x * v.x + v.y * v.y + v.z * v.z + v.w * v.w;
#pragma unroll
    for (int off = 1; off < 64; off <<= 1) {
        s1 += __shfl_xor(s1, off, 64);
        s2 += __shfl_xor(s2, off, 64);
    }
    if (lane == 0) { red[0][wid] = s1; red[1][wid] = s2; }
    __syncthreads();
    s1 = red[0][0] + red[0][1] + red[0][2] + red[0][3];
    s2 = red[1][0] + red[1][1] + red[1][2] + red[1][3];
    float mu = s1 * (1.f / 1024.f);
    float var = s2 * (1.f / 1024.f) - mu * mu;
    float rstd = rsqrtf(var + 1e-5f);
    f32x4 gv = ((const f32x4*)g)[tid], bev = ((const f32x4*)be)[tid];
    f32x4 y = (v - mu) * rstd * gv + bev;
    if (xout) ((f32x4*)xout)[idx] = y;
    if (xb) {
        us4 ob;
        ob.x = f2bf(y.x); ob.y = f2bf(y.y); ob.z = f2bf(y.z); ob.w = f2bf(y.w);
        ((us4*)xb)[idx] = ob;
    }
}

// ---------- host ----------
extern "C" void kernel_launch(void* const* d_in, const int* in_sizes, int n_in,
                              void* d_out, int out_size, void* d_ws, size_t ws_size,
                              hipStream_t stream) {
    const float* src    = (const float*)d_in[0];
    const int*   coords = (const int*)d_in[1];
    const float* Wq     = (const float*)d_in[2];
    const float* Wk     = (const float*)d_in[3];
    const float* Wv     = (const float*)d_in[4];
    const float* Wo     = (const float*)d_in[5];
    const float* W1     = (const float*)d_in[6];
    const float* b1     = (const float*)d_in[7];
    const float* W2     = (const float*)d_in[8];
    const float* b2     = (const float*)d_in[9];
    const float* g1     = (const float*)d_in[10];
    const float* be1    = (const float*)d_in[11];
    const float* g2     = (const float*)d_in[12];
    const float* be2    = (const float*)d_in[13];
    float* out = (float*)d_out;

    char* ws = (char*)d_ws;
    size_t off = 0;
    auto alloc = [&](size_t bytes) { size_t o = off; off += (bytes + 255) & ~(size_t)255; return o; };

    const size_t BT = 4096;  // B*N rows
    // region A (reused by h1 later): qkv + attno + vt
    size_t qkv_off   = alloc(BT * 3072 * 2);           // 25.2 MB
    size_t attno_off = alloc(BT * 1024 * 2);           //  8.4 MB
    size_t vt_off    = alloc((size_t)64 * 64 * 1024 * 2); // 8.4 MB
    size_t x_off    = alloc(BT * 1024 * 4);            // 16.8 MB
    // the next four regions (33.55 MB contiguous) are dead by FF2 time -> FF2 partials
    size_t ffs_off  = alloc(BT * 1024 * 4);            // Wo partials [2][4096][1024]bf16 (16.78 MB)
    size_t srcb_off = alloc(BT * 1024 * 2);            // srcb, reused as xb   (8.39 MB)
    size_t wqkv_off = alloc((size_t)3072 * 1024 * 2);  // (6.29 MB)
    size_t wo_off   = alloc((size_t)1024 * 1024 * 2);  // (2.10 MB)
    size_t w1_off   = alloc((size_t)4096 * 1024 * 2);
    size_t w2_off   = alloc((size_t)1024 * 4096 * 2);
    (void)ws_size; (void)in_sizes; (void)n_in; (void)out_size;

    unsigned short* qkv   = (unsigned short*)(ws + qkv_off);
    unsigned short* attno = (unsigned short*)(ws + attno_off);
    unsigned short* vt    = (unsigned short*)(ws + vt_off);
    float*          x     = (float*)(ws + x_off);
    unsigned short* pbWo  = (unsigned short*)(ws + ffs_off);   // [2][4096][1024] bf16
    unsigned short* pbFF  = (unsigned short*)(ws + ffs_off);   // [4][4096][1024] bf16 (spans ffs..wo)
    unsigned short* srcb  = (unsigned short*)(ws + srcb_off);
    unsigned short* xb    = (unsigned short*)(ws + srcb_off);
    unsigned short* wqkvb = (unsigned short*)(ws + wqkv_off);
    unsigned short* wob   = (unsigned short*)(ws + wo_off);
    unsigned short* w1b   = (unsigned short*)(ws + w1_off);
    unsigned short* w2b   = (unsigned short*)(ws + w2_off);
    unsigned short* h1    = (unsigned short*)(ws + qkv_off);  // reuse region A

    auto cvt = [&](const float* in, unsigned short* o, size_t n) {
        int n4 = (int)(n / 4);
        cvt_kernel<<<(n4 + 255) / 256, 256, 0, stream>>>(in, o, n4);
    };
    // converts
    cvt(src, srcb, BT * 1024);
    cvt(Wq, wqkvb, 1024 * 1024);
    cvt(Wk, wqkvb + 1024 * 1024, 1024 * 1024);
    cvt(Wv, wqkvb + 2 * 1024 * 1024, 1024 * 1024);
    cvt(Wo, wob, 1024 * 1024);
    cvt(W1, w1b, 4096 * 1024);
    cvt(W2, w2b, 1024 * 4096);

    // QKV = srcb @ Wqkv^T   (M=4096, N=3072, K=1024)
    gemm_bt<0><<<dim3(3072 / BN, 4096 / BM), 256, 0, stream>>>(srcb, wqkvb, nullptr, qkv, nullptr, 4096, 3072, 1024);
    // V transpose
    transpose_v<<<dim3(16, 64), 256, 0, stream>>>(qkv, vt);
    // attention (128 q rows per block)
    attn_kernel<<<dim3(8, 64), 256, 0, stream>>>(qkv, coords, vt, attno);
    // Wo partials: attno @ Wo^T, 2-way split-K (512 blocks = 2/CU)
    gemm_splitk<<<dim3(1024 / BN, 4096 / BM, 2), 256, 0, stream>>>(attno, wob, pbWo, 1024, 1024, 512);
    // x = LN(src + p0 + p1); xb = bf16(x)
    ln_sum_kernel<<<4096, 256, 0, stream>>>(src, pbWo, 2, nullptr, g1, be1, x, xb);
    // h1 = gelu(xb @ W1^T + b1)   -- 256^2 counted-vmcnt kernel, full 256-block grid
    gemm256<2><<<dim3(4096 / 256, 4096 / 256), 512, 0, stream>>>(xb, w1b, nullptr, h1, b1, 4096, 4096, 1024);
    // FF2 partials: h1 @ W2^T, 4-way split-K (1024 blocks = 4/CU)
    gemm_splitk<<<dim3(1024 / BN, 4096 / BM, 4), 256, 0, stream>>>(h1, w2b, pbFF, 1024, 4096, 1024);
    // out = LN(x + p0+p1+p2+p3 + b2)
    ln_sum_kernel<<<4096, 256, 0, stream>>>(x, pbFF, 4, b2, g2, be2, out, nullptr);
}

// Round 9
// 350.093 us; speedup vs baseline: 1.0672x; 1.0672x over previous
//
#include <hip/hip_runtime.h>
#include <hip/hip_bf16.h>
#include <math.h>

#define DEV __device__ __forceinline__

typedef __attribute__((ext_vector_type(4))) float f32x4;
typedef __attribute__((ext_vector_type(16))) float f32x16;
typedef __attribute__((ext_vector_type(8))) short bf16x8;
typedef __attribute__((ext_vector_type(4))) unsigned short us4;

// ---------- scalar helpers ----------
DEV unsigned short f2bf(float f) {
    union { float f; unsigned u; } v; v.f = f;
    unsigned r = v.u + 0x7FFF + ((v.u >> 16) & 1);
    return (unsigned short)(r >> 16);
}

DEV float bf2f(unsigned short u) {
    union { unsigned u; float f; } v; v.u = (unsigned)u << 16; return v.f;
}

// tanh-form GELU (overflow-safe). ~1e-3 abs err vs exact-erf GELU — invisible
// under the immediate bf16 cast of h1. Replaces erff (~40+ VALU ops) with one
// v_exp_f32 + ~10 VALU. The FF1 epilogue runs this 128x/thread, fully exposed
// (grid = 1 block/CU), so this is a direct tail-time cut.
DEV float gelu_fast(float v) {
    float u = 0.7978845608f * v * (1.0f + 0.044715f * v * v);
    float e = __expf(-2.0f * fabsf(u));
    float th = (1.0f - e) / (1.0f + e);
    th = copysignf(th, u);
    return 0.5f * v * (1.0f + th);
}

DEV void async16(const void* g, void* l) {
    __builtin_amdgcn_global_load_lds(
        (const __attribute__((address_space(1))) void*)g,
        (__attribute__((address_space(3))) void*)l, 16, 0, 0);
}

// bijective XCD-aware remap (m204): chunked so consecutive wgids share an XCD's L2
DEV int xcd_swizzle(int flat, int nwg) {
    int q = nwg >> 3, r8 = nwg & 7;
    int xcd = flat & 7, idx = flat >> 3;
    return (xcd < r8 ? xcd * (q + 1) : r8 * (q + 1) + (xcd - r8) * q) + idx;
}

// ---------- f32 -> bf16 convert ----------
__global__ void cvt_kernel(const float* __restrict__ in, unsigned short* __restrict__ out, int n4) {
    int i = blockIdx.x * blockDim.x + threadIdx.x;
    if (i >= n4) return;
    f32x4 v = ((const f32x4*)in)[i];
    us4 o;
    o.x = f2bf(v.x); o.y = f2bf(v.y); o.z = f2bf(v.z); o.w = f2bf(v.w);
    ((us4*)out)[i] = o;
}

// ---------- GEMM 128x128 (m97 structure): C[M,N] = A[M,K] * B[N,K]^T ----------
// EPI: 0 = bf16 out, 1 = f32 out, 2 = +bias, fast GELU, bf16 out, 3 = +bias, f32 out
#define BM 128
#define BN 128
#define BKK 64

template<int EPI>
__global__ __launch_bounds__(256) void gemm_bt(
    const unsigned short* __restrict__ A,
    const unsigned short* __restrict__ B,
    float* __restrict__ Cf, unsigned short* __restrict__ Cb,
    const float* __restrict__ bias,
    int M, int N, int K)
{
    __shared__ unsigned short As[BM * BKK];
    __shared__ unsigned short Bs[BN * BKK];

    const int tid  = threadIdx.x;
    const int wid  = tid >> 6, lane = tid & 63;
    const int l15  = lane & 15, l16 = lane >> 4;
    const int wr   = wid >> 1, wc = wid & 1;

    const int nwg  = gridDim.x * gridDim.y;
    const int flat = xcd_swizzle(blockIdx.y * gridDim.x + blockIdx.x, nwg);
    const int row0 = (flat / gridDim.x) * BM;
    const int col0 = (flat % gridDim.x) * BN;

    f32x4 acc[4][4] = {};

    const int nkt = K / BKK;
    for (int kt = 0; kt < nkt; ++kt) {
        const int k0 = kt * BKK;
        __syncthreads();
        // stage A and B tiles: linear LDS dest, inverse-swizzled global source (rule 21)
#pragma unroll
        for (int i = 0; i < 4; ++i) {
            int c = i * 256 + tid;          // chunk index, 16B per chunk
            int row = c >> 3, slot = c & 7;
            int ks = (slot ^ (row & 7)) * 8;
            async16(A + (size_t)(row0 + row) * K + k0 + ks, (char*)As + c * 16);
            async16(B + (size_t)(col0 + row) * K + k0 + ks, (char*)Bs + c * 16);
        }
        __syncthreads();   // compiler drains vmcnt before barrier
#pragma unroll
        for (int kk = 0; kk < 2; ++kk) {
            bf16x8 af[4], bfr[4];
#pragma unroll
            for (int m = 0; m < 4; ++m) {
                int r = wr * 64 + m * 16 + l15;
                int slot = (kk * 4 + l16) ^ (r & 7);
                af[m] = *(const bf16x8*)((const char*)As + r * 128 + slot * 16);
            }
#pragma unroll
            for (int n = 0; n < 4; ++n) {
                int r = wc * 64 + n * 16 + l15;
                int slot = (kk * 4 + l16) ^ (r & 7);
                bfr[n] = *(const bf16x8*)((const char*)Bs + r * 128 + slot * 16);
            }
#pragma unroll
            for (int m = 0; m < 4; ++m)
#pragma unroll
                for (int n = 0; n < 4; ++n)
                    acc[m][n] = __builtin_amdgcn_mfma_f32_16x16x32_bf16(af[m], bfr[n], acc[m][n], 0, 0, 0);
        }
    }

    // epilogue: C/D layout col=lane&15, row=(lane>>4)*4+reg  [m89/m91]
#pragma unroll
    for (int m = 0; m < 4; ++m) {
        int grow = row0 + wr * 64 + m * 16 + l16 * 4;
#pragma unroll
        for (int n = 0; n < 4; ++n) {
            int gcol = col0 + wc * 64 + n * 16 + l15;
            float bv = (EPI >= 2) ? bias[gcol] : 0.f;
#pragma unroll
            for (int r = 0; r < 4; ++r) {
                float v = acc[m][n][r];
                size_t idx = (size_t)(grow + r) * N + gcol;
                if (EPI == 0) {
                    Cb[idx] = f2bf(v);
                } else if (EPI == 1) {
                    Cf[idx] = v;
                } else if (EPI == 2) {
                    Cb[idx] = f2bf(gelu_fast(v + bv));
                } else {
                    Cf[idx] = v + bv;
                }
            }
        }
    }
}

// ---------- split-K GEMM 128x128: P[s][M][N] = A[:, s*Klen:(s+1)*Klen] * B^T ----------
// blockIdx.z = split s. Partials bf16; summed (plus optional bias) in ln_sum_kernel.
__global__ __launch_bounds__(256) void gemm_splitk(
    const unsigned short* __restrict__ A,
    const unsigned short* __restrict__ B,
    unsigned short* __restrict__ Pb,
    int N, int Kld, int Klen)
{
    __shared__ unsigned short As[BM * BKK];
    __shared__ unsigned short Bs[BN * BKK];

    const int tid  = threadIdx.x;
    const int wid  = tid >> 6, lane = tid & 63;
    const int l15  = lane & 15, l16 = lane >> 4;
    const int wr   = wid >> 1, wc = wid & 1;

    const int s = blockIdx.z;
    const unsigned short* Ab = A + (size_t)s * Klen;
    const unsigned short* Bb = B + (size_t)s * Klen;

    const int nwg  = gridDim.x * gridDim.y;
    const int flat = xcd_swizzle(blockIdx.y * gridDim.x + blockIdx.x, nwg);
    const int row0 = (flat / gridDim.x) * BM;
    const int col0 = (flat % gridDim.x) * BN;

    f32x4 acc[4][4] = {};

    const int nkt = Klen / BKK;
    for (int kt = 0; kt < nkt; ++kt) {
        const int k0 = kt * BKK;
        __syncthreads();
#pragma unroll
        for (int i = 0; i < 4; ++i) {
            int c = i * 256 + tid;
            int row = c >> 3, slot = c & 7;
            int ks = (slot ^ (row & 7)) * 8;
            async16(Ab + (size_t)(row0 + row) * Kld + k0 + ks, (char*)As + c * 16);
            async16(Bb + (size_t)(col0 + row) * Kld + k0 + ks, (char*)Bs + c * 16);
        }
        __syncthreads();
#pragma unroll
        for (int kk = 0; kk < 2; ++kk) {
            bf16x8 af[4], bfr[4];
#pragma unroll
            for (int m = 0; m < 4; ++m) {
                int r = wr * 64 + m * 16 + l15;
                int slot = (kk * 4 + l16) ^ (r & 7);
                af[m] = *(const bf16x8*)((const char*)As + r * 128 + slot * 16);
            }
#pragma unroll
            for (int n = 0; n < 4; ++n) {
                int r = wc * 64 + n * 16 + l15;
                int slot = (kk * 4 + l16) ^ (r & 7);
                bfr[n] = *(const bf16x8*)((const char*)Bs + r * 128 + slot * 16);
            }
#pragma unroll
            for (int m = 0; m < 4; ++m)
#pragma unroll
                for (int n = 0; n < 4; ++n)
                    acc[m][n] = __builtin_amdgcn_mfma_f32_16x16x32_bf16(af[m], bfr[n], acc[m][n], 0, 0, 0);
        }
    }

    unsigned short* P = Pb + (size_t)s * (size_t)(gridDim.y * BM) * N;
#pragma unroll
    for (int m = 0; m < 4; ++m) {
        int grow = row0 + wr * 64 + m * 16 + l16 * 4;
#pragma unroll
        for (int n = 0; n < 4; ++n) {
            int gcol = col0 + wc * 64 + n * 16 + l15;
#pragma unroll
            for (int r = 0; r < 4; ++r)
                P[(size_t)(grow + r) * N + gcol] = f2bf(acc[m][n][r]);
        }
    }
}

// ---------- GEMM 256x256, 8 waves, double-buffered with COUNTED vmcnt (T4/m218) ----------
template<int EPI>
__global__ __launch_bounds__(512, 2) void gemm256(
    const unsigned short* __restrict__ A,
    const unsigned short* __restrict__ B,
    float* __restrict__ Cf, unsigned short* __restrict__ Cb,
    const float* __restrict__ bias,
    int M, int N, int K)
{
    __shared__ unsigned short As[2][256 * 64];   // 32 KB x2
    __shared__ unsigned short Bs[2][256 * 64];   // 32 KB x2  -> 128 KB total

    const int tid = threadIdx.x;
    const int wid = tid >> 6, lane = tid & 63;
    const int l15 = lane & 15, l16 = lane >> 4;
    const int wr = wid >> 2, wc = wid & 3;       // 2 (M) x 4 (N) waves, each 128x64

    const int nwg  = gridDim.x * gridDim.y;
    const int flat = xcd_swizzle(blockIdx.y * gridDim.x + blockIdx.x, nwg);
    const int row0 = (flat / gridDim.x) * 256;
    const int col0 = (flat % gridDim.x) * 256;

    f32x4 acc[8][4] = {};

    auto stage = [&](int buf, int k0) {          // 8 global_load_lds per thread
#pragma unroll
        for (int i = 0; i < 4; ++i) {
            int c = i * 512 + tid;               // 2048 chunks of 16B per matrix
            int row = c >> 3, slot = c & 7;
            int ks = (slot ^ (row & 7)) * 8;
            async16(A + (size_t)(row0 + row) * K + k0 + ks, (char*)As[buf] + c * 16);
            async16(B + (size_t)(col0 + row) * K + k0 + ks, (char*)Bs[buf] + c * 16);
        }
    };

    stage(0, 0);
    int cur = 0;
    const int nkt = K / 64;
    for (int kt = 0; kt < nkt; ++kt) {
        if (kt + 1 < nkt) {
            stage(cur ^ 1, (kt + 1) * 64);       // issue next tile FIRST
            __builtin_amdgcn_sched_barrier(0);
            asm volatile("s_waitcnt vmcnt(8)" ::: "memory");   // current tile's 8 done; next 8 fly
        } else {
            __builtin_amdgcn_sched_barrier(0);
            asm volatile("s_waitcnt vmcnt(0)" ::: "memory");   // last tile: full drain
        }
        __builtin_amdgcn_sched_barrier(0);
        __builtin_amdgcn_s_barrier();            // publish buf[cur]
        __builtin_amdgcn_sched_barrier(0);
#pragma unroll
        for (int kk = 0; kk < 2; ++kk) {
            bf16x8 af[8], bfr[4];
#pragma unroll
            for (int m = 0; m < 8; ++m) {
                int r = wr * 128 + m * 16 + l15;
                int slot = (kk * 4 + l16) ^ (r & 7);
                af[m] = *(const bf16x8*)((const char*)As[cur] + r * 128 + slot * 16);
            }
#pragma unroll
            for (int n = 0; n < 4; ++n) {
                int r = wc * 64 + n * 16 + l15;
                int slot = (kk * 4 + l16) ^ (r & 7);
                bfr[n] = *(const bf16x8*)((const char*)Bs[cur] + r * 128 + slot * 16);
            }
            __builtin_amdgcn_s_setprio(1);
#pragma unroll
            for (int m = 0; m < 8; ++m)
#pragma unroll
                for (int n = 0; n < 4; ++n)
                    acc[m][n] = __builtin_amdgcn_mfma_f32_16x16x32_bf16(af[m], bfr[n], acc[m][n], 0, 0, 0);
            __builtin_amdgcn_s_setprio(0);
        }
        __builtin_amdgcn_sched_barrier(0);
        __builtin_amdgcn_s_barrier();            // all waves done reading buf[cur]
        __builtin_amdgcn_sched_barrier(0);       // before next iter overwrites it
        cur ^= 1;
    }

#pragma unroll
    for (int m = 0; m < 8; ++m) {
        int grow = row0 + wr * 128 + m * 16 + l16 * 4;
#pragma unroll
        for (int n = 0; n < 4; ++n) {
            int gcol = col0 + wc * 64 + n * 16 + l15;
            float bv = (EPI >= 2) ? bias[gcol] : 0.f;
#pragma unroll
            for (int r = 0; r < 4; ++r) {
                float v = acc[m][n][r];
                size_t idx = (size_t)(grow + r) * N + gcol;
                if (EPI == 0) {
                    Cb[idx] = f2bf(v);
                } else if (EPI == 1) {
                    Cf[idx] = v;
                } else if (EPI == 2) {
                    Cb[idx] = f2bf(gelu_fast(v + bv));
                } else {
                    Cf[idx] = v + bv;
                }
            }
        }
    }
}

// ---------- V transpose: qkv V-part [B,N,H,64] -> vt [B,H,64,N] ----------
__global__ __launch_bounds__(256) void transpose_v(const unsigned short* __restrict__ qkv,
                                                   unsigned short* __restrict__ vt)
{
    __shared__ unsigned short t[64][72];
    const int n0 = blockIdx.x * 64;
    const int bh = blockIdx.y;
    const int b = bh >> 4, h = bh & 15;
    const int tid = threadIdx.x;
#pragma unroll
    for (int i = 0; i < 2; ++i) {
        int c = i * 256 + tid;
        int row = c >> 3, col0 = (c & 7) * 8;
        const unsigned short* src = qkv + (size_t)(b * 1024 + n0 + row) * 3072 + 2048 + h * 64 + col0;
        bf16x8 v = *(const bf16x8*)src;
#pragma unroll
        for (int j = 0; j < 8; ++j) t[row][col0 + j] = (unsigned short)v[j];
    }
    __syncthreads();
#pragma unroll
    for (int i = 0; i < 2; ++i) {
        int c = i * 256 + tid;
        int hd = c >> 3, col0 = (c & 7) * 8;
        bf16x8 v;
#pragma unroll
        for (int j = 0; j < 8; ++j) v[j] = (short)t[col0 + j][hd];
        *(bf16x8*)(vt + ((size_t)bh * 64 + hd) * 1024 + n0 + col0) = v;
    }
}

// ---------- fused attention: swapped QK^T (S^T), 32x32 MFMA, in-register softmax ----------
// Wave owns 32 q rows (q = lane&31). Block = 4 waves = 128 q. Grid: (1024/128, B*H).
__global__ __launch_bounds__(256) void attn_kernel(const unsigned short* __restrict__ qkv,
                                                   const int* __restrict__ coords,
                                                   const unsigned short* __restrict__ vt,
                                                   unsigned short* __restrict__ out)
{
    __shared__ unsigned short Ks[2][64 * 64];   // K tile, rows = kv, swizzled
    __shared__ unsigned short Vs[2][64 * 64];   // V^T tile, rows = d, swizzled
    __shared__ float cF[1024 * 2];              // slope2-scaled coords for this b

    const int tid = threadIdx.x, wid = tid >> 6, lane = tid & 63;
    const int l31 = lane & 31, hi = lane >> 5;
    const int q0 = blockIdx.x * 128;
    const int bh = blockIdx.y;
    const int b = bh >> 4, h = bh & 15;
    const float LOG2E = 1.4426950408889634f;
    const float slope2 = exp2f(-0.5f * (float)(h + 1)) * LOG2E;
    const float scale2 = 0.125f * LOG2E;

    // staging descriptors (rule 21: linear LDS dest, inverse-swizzled global src)
    const int c0 = tid,       r0c = c0 >> 3, ks0 = ((c0 & 7) ^ (r0c & 7)) * 8;
    const int c1 = 256 + tid, r1c = c1 >> 3, ks1 = ((c1 & 7) ^ (r1c & 7)) * 8;
    const unsigned short* kbase = qkv + (size_t)(b * 1024) * 3072 + 1024 + h * 64;
    const unsigned short* vbase = vt + (size_t)bh * 64 * 1024;

    // pre-scale coords into LDS (bias = |qxs-kxs| + |qys-kys|, log2 domain)
    {
        const int2* cp = (const int2*)coords + b * 1024;
#pragma unroll
        for (int i = 0; i < 4; ++i) {
            int kv = i * 256 + tid;
            int2 c = cp[kv];
            cF[kv * 2]     = slope2 * (float)c.x;
            cF[kv * 2 + 1] = slope2 * (float)c.y;
        }
    }

    const int qrow = q0 + wid * 32 + l31;
    // Q as B-fragment: row=q (lane&31), k = c16*16 + hi*8 + j
    bf16x8 qf[4];
    {
        const unsigned short* qp = qkv + (size_t)(b * 1024 + qrow) * 3072 + h * 64 + hi * 8;
        qf[0] = *(const bf16x8*)qp;
        qf[1] = *(const bf16x8*)(qp + 16);
        qf[2] = *(const bf16x8*)(qp + 32);
        qf[3] = *(const bf16x8*)(qp + 48);
    }
    float qxs, qys;
    {
        int2 qc = ((const int2*)coords)[b * 1024 + qrow];
        qxs = slope2 * (float)qc.x; qys = slope2 * (float)qc.y;
    }

    float mr = -1e30f, lr = 0.f;
    f32x16 o0 = (f32x16)0.f, o1 = (f32x16)0.f;   // O^T tiles: d 0-31, 32-63

    // prologue: stage tile 0
    async16(kbase + (size_t)r0c * 3072 + ks0, (char*)Ks[0] + c0 * 16);
    async16(kbase + (size_t)r1c * 3072 + ks1, (char*)Ks[0] + c1 * 16);
    async16(vbase + (size_t)r0c * 1024 + ks0, (char*)Vs[0] + c0 * 16);
    async16(vbase + (size_t)r1c * 1024 + ks1, (char*)Vs[0] + c1 * 16);
    int cur = 0;

    for (int t = 0; t < 16; ++t) {
        const int kv0 = t * 64;
        __syncthreads();                    // drains vmcnt + coord writes
        if (t < 15) {                       // prefetch next tile under compute
            const int kv1 = kv0 + 64;
            async16(kbase + (size_t)(kv1 + r0c) * 3072 + ks0, (char*)Ks[cur ^ 1] + c0 * 16);
            async16(kbase + (size_t)(kv1 + r1c) * 3072 + ks1, (char*)Ks[cur ^ 1] + c1 * 16);
            async16(vbase + (size_t)r0c * 1024 + kv1 + ks0, (char*)Vs[cur ^ 1] + c0 * 16);
            async16(vbase + (size_t)r1c * 1024 + kv1 + ks1, (char*)Vs[cur ^ 1] + c1 * 16);
        }

        // S^T[kv][q] = K·Q^T : A = K (rows kv), B = Q (rows q)
        f32x16 s0 = (f32x16)0.f, s1 = (f32x16)0.f;
        __builtin_amdgcn_s_setprio(1);
#pragma unroll
        for (int c16 = 0; c16 < 4; ++c16) {
            int slot = ((c16 * 2 + hi) ^ (l31 & 7)) * 16;
            bf16x8 k0f = *(const bf16x8*)((const char*)Ks[cur] + l31 * 128 + slot);
            bf16x8 k1f = *(const bf16x8*)((const char*)Ks[cur] + (32 + l31) * 128 + slot);
            s0 = __builtin_amdgcn_mfma_f32_32x32x16_bf16(k0f, qf[c16], s0, 0, 0, 0);
            s1 = __builtin_amdgcn_mfma_f32_32x32x16_bf16(k1f, qf[c16], s1, 0, 0, 0);
        }
        __builtin_amdgcn_s_setprio(0);

        // bias: s_log2 = s*scale2 + |qxs-kxs| + |qys-kys|
        // lane's kv rows: (r&3) + 8*(r>>2) + 4*hi + 32*T   [m74/m101 C layout]
#pragma unroll
        for (int T = 0; T < 2; ++T) {
            f32x16& S = T ? s1 : s0;
#pragma unroll
            for (int u = 0; u < 4; ++u) {
                int kvb = kv0 + T * 32 + u * 8 + hi * 4;
                f32x4 ca = *(const f32x4*)&cF[kvb * 2];
                f32x4 cb = *(const f32x4*)&cF[kvb * 2 + 4];
                S[4*u+0] = S[4*u+0] * scale2 + (fabsf(qxs - ca.x) + fabsf(qys - ca.y));
                S[4*u+1] = S[4*u+1] * scale2 + (fabsf(qxs - ca.z) + fabsf(qys - ca.w));
                S[4*u+2] = S[4*u+2] * scale2 + (fabsf(qxs - cb.x) + fabsf(qys - cb.y));
                S[4*u+3] = S[4*u+3] * scale2 + (fabsf(qxs - cb.z) + fabsf(qys - cb.w));
            }
        }

        // online softmax (per-lane q row): in-lane max + one cross-half shfl
        float pm = s0[0];
#pragma unroll
        for (int i = 1; i < 16; ++i) pm = fmaxf(pm, s0[i]);
#pragma unroll
        for (int i = 0; i < 16; ++i) pm = fmaxf(pm, s1[i]);
        pm = fmaxf(pm, __shfl_xor(pm, 32, 64));
        if (__any(pm > mr + 8.0f)) {        // defer-max (T13): rescale only on real growth
            float mn = fmaxf(mr, pm);
            float corr = exp2f(mr - mn);
            mr = mn;
            lr *= corr;
#pragma unroll
            for (int i = 0; i < 16; ++i) { o0[i] *= corr; o1[i] *= corr; }
        }
        float sum = 0.f;
#pragma unroll
        for (int i = 0; i < 16; ++i) { float p = exp2f(s0[i] - mr); s0[i] = p; sum += p; }
#pragma unroll
        for (int i = 0; i < 16; ++i) { float p = exp2f(s1[i] - mr); s1[i] = p; sum += p; }
        sum += __shfl_xor(sum, 32, 64);
        lr += sum;

        // P -> bf16 B-fragments via cvt_pk + permlane32_swap (T12)
        bf16x8 pf[4];
#pragma unroll
        for (int c = 0; c < 4; ++c) {
            const f32x16& S = (c < 2) ? s0 : s1;
            const int e = (c & 1) * 8;
            unsigned x0, x1, y0, y1;
            asm("v_cvt_pk_bf16_f32 %0, %1, %2" : "=v"(x0) : "v"(S[e+0]), "v"(S[e+1]));
            asm("v_cvt_pk_bf16_f32 %0, %1, %2" : "=v"(x1) : "v"(S[e+2]), "v"(S[e+3]));
            asm("v_cvt_pk_bf16_f32 %0, %1, %2" : "=v"(y0) : "v"(S[e+4]), "v"(S[e+5]));
            asm("v_cvt_pk_bf16_f32 %0, %1, %2" : "=v"(y1) : "v"(S[e+6]), "v"(S[e+7]));
            asm("v_permlane32_swap_b32 %0, %1" : "+v"(x0), "+v"(y0));
            asm("v_permlane32_swap_b32 %0, %1" : "+v"(x1), "+v"(y1));
            union { unsigned u[4]; bf16x8 v; } pk_;
            pk_.u[0] = x0; pk_.u[1] = x1; pk_.u[2] = y0; pk_.u[3] = y1;
            pf[c] = pk_.v;
        }

        // O^T += V^T · P : A = V^T (rows d), B = P (rows q)
        __builtin_amdgcn_s_setprio(1);
#pragma unroll
        for (int c = 0; c < 4; ++c) {
            int slot = ((c * 2 + hi) ^ (l31 & 7)) * 16;
            bf16x8 v0 = *(const bf16x8*)((const char*)Vs[cur] + l31 * 128 + slot);
            bf16x8 v1 = *(const bf16x8*)((const char*)Vs[cur] + (32 + l31) * 128 + slot);
            o0 = __builtin_amdgcn_mfma_f32_32x32x16_bf16(v0, pf[c], o0, 0, 0, 0);
            o1 = __builtin_amdgcn_mfma_f32_32x32x16_bf16(v1, pf[c], o1, 0, 0, 0);
        }
        __builtin_amdgcn_s_setprio(0);
        cur ^= 1;
    }

    const float inv = 1.0f / lr;
    unsigned short* op = out + (size_t)(b * 1024 + qrow) * 1024 + h * 64;
#pragma unroll
    for (int Td = 0; Td < 2; ++Td) {
        const f32x16& O = Td ? o1 : o0;
#pragma unroll
        for (int u = 0; u < 4; ++u) {
            us4 w;
            w.x = f2bf(O[4*u+0] * inv);
            w.y = f2bf(O[4*u+1] * inv);
            w.z = f2bf(O[4*u+2] * inv);
            w.w = f2bf(O[4*u+3] * inv);
            *(us4*)(op + Td * 32 + u * 8 + hi * 4) = w;
        }
    }
}

// ---------- LayerNorm(a + sum_{s<nsplit} P[s] + bias?) -> f32 out (opt) + bf16 out (opt) ----------
__global__ __launch_bounds__(256) void ln_sum_kernel(const float* __restrict__ a,
                                                     const unsigned short* __restrict__ pb, int nsplit,
                                                     const float* __restrict__ bias,
                                                     const float* __restrict__ g, const float* __restrict__ be,
                                                     float* __restrict__ xout, unsigned short* __restrict__ xb)
{
    __shared__ float red[2][4];
    const int row = blockIdx.x, tid = threadIdx.x;
    const int wid = tid >> 6, lane = tid & 63;
    const size_t idx = (size_t)row * 256 + tid;
    f32x4 v = ((const f32x4*)a)[idx];
    for (int s = 0; s < nsplit; ++s) {
        us4 p = ((const us4*)pb)[(size_t)s * 1048576 + idx];   // stride = 4096*1024/4 us4
        v.x += bf2f(p.x); v.y += bf2f(p.y); v.z += bf2f(p.z); v.w += bf2f(p.w);
    }
    if (bias) {
        f32x4 bv = ((const f32x4*)bias)[tid];
        v.x += bv.x; v.y += bv.y; v.z += bv.z; v.w += bv.w;
    }
    float s1 = v.x + v.y + v.z + v.w;
    float s2 = v.x * v.x + v.y * v.y + v.z * v.z + v.w * v.w;
#pragma unroll
    for (int off = 1; off < 64; off <<= 1) {
        s1 += __shfl_xor(s1, off, 64);
        s2 += __shfl_xor(s2, off, 64);
    }
    if (lane == 0) { red[0][wid] = s1; red[1][wid] = s2; }
    __syncthreads();
    s1 = red[0][0] + red[0][1] + red[0][2] + red[0][3];
    s2 = red[1][0] + red[1][1] + red[1][2] + red[1][3];
    float mu = s1 * (1.f / 1024.f);
    float var = s2 * (1.f / 1024.f) - mu * mu;
    float rstd = rsqrtf(var + 1e-5f);
    f32x4 gv = ((const f32x4*)g)[tid], bev = ((const f32x4*)be)[tid];
    f32x4 y = (v - mu) * rstd * gv + bev;
    if (xout) ((f32x4*)xout)[idx] = y;
    if (xb) {
        us4 ob;
        ob.x = f2bf(y.x); ob.y = f2bf(y.y); ob.z = f2bf(y.z); ob.w = f2bf(y.w);
        ((us4*)xb)[idx] = ob;
    }
}

// ---------- host ----------
extern "C" void kernel_launch(void* const* d_in, const int* in_sizes, int n_in,
                              void* d_out, int out_size, void* d_ws, size_t ws_size,
                              hipStream_t stream) {
    const float* src    = (const float*)d_in[0];
    const int*   coords = (const int*)d_in[1];
    const float* Wq     = (const float*)d_in[2];
    const float* Wk     = (const float*)d_in[3];
    const float* Wv     = (const float*)d_in[4];
    const float* Wo     = (const float*)d_in[5];
    const float* W1     = (const float*)d_in[6];
    const float* b1     = (const float*)d_in[7];
    const float* W2     = (const float*)d_in[8];
    const float* b2     = (const float*)d_in[9];
    const float* g1     = (const float*)d_in[10];
    const float* be1    = (const float*)d_in[11];
    const float* g2     = (const float*)d_in[12];
    const float* be2    = (const float*)d_in[13];
    float* out = (float*)d_out;

    char* ws = (char*)d_ws;
    size_t off = 0;
    auto alloc = [&](size_t bytes) { size_t o = off; off += (bytes + 255) & ~(size_t)255; return o; };

    const size_t BT = 4096;  // B*N rows
    // region A (reused by h1 later): qkv + attno + vt
    size_t qkv_off   = alloc(BT * 3072 * 2);           // 25.2 MB
    size_t attno_off = alloc(BT * 1024 * 2);           //  8.4 MB
    size_t vt_off    = alloc((size_t)64 * 64 * 1024 * 2); // 8.4 MB
    size_t x_off    = alloc(BT * 1024 * 4);            // 16.8 MB
    // the next four regions (33.55 MB contiguous) are dead by FF2 time -> FF2 partials
    size_t ffs_off  = alloc(BT * 1024 * 4);            // Wo partials [2][4096][1024]bf16 (16.78 MB)
    size_t srcb_off = alloc(BT * 1024 * 2);            // srcb, reused as xb   (8.39 MB)
    size_t wqkv_off = alloc((size_t)3072 * 1024 * 2);  // (6.29 MB)
    size_t wo_off   = alloc((size_t)1024 * 1024 * 2);  // (2.10 MB)
    size_t w1_off   = alloc((size_t)4096 * 1024 * 2);
    size_t w2_off   = alloc((size_t)1024 * 4096 * 2);
    (void)ws_size; (void)in_sizes; (void)n_in; (void)out_size;

    unsigned short* qkv   = (unsigned short*)(ws + qkv_off);
    unsigned short* attno = (unsigned short*)(ws + attno_off);
    unsigned short* vt    = (unsigned short*)(ws + vt_off);
    float*          x     = (float*)(ws + x_off);
    unsigned short* pbWo  = (unsigned short*)(ws + ffs_off);   // [2][4096][1024] bf16
    unsigned short* pbFF  = (unsigned short*)(ws + ffs_off);   // [4][4096][1024] bf16 (spans ffs..wo)
    unsigned short* srcb  = (unsigned short*)(ws + srcb_off);
    unsigned short* xb    = (unsigned short*)(ws + srcb_off);
    unsigned short* wqkvb = (unsigned short*)(ws + wqkv_off);
    unsigned short* wob   = (unsigned short*)(ws + wo_off);
    unsigned short* w1b   = (unsigned short*)(ws + w1_off);
    unsigned short* w2b   = (unsigned short*)(ws + w2_off);
    unsigned short* h1    = (unsigned short*)(ws + qkv_off);  // reuse region A

    auto cvt = [&](const float* in, unsigned short* o, size_t n) {
        int n4 = (int)(n / 4);
        cvt_kernel<<<(n4 + 255) / 256, 256, 0, stream>>>(in, o, n4);
    };
    // converts
    cvt(src, srcb, BT * 1024);
    cvt(Wq, wqkvb, 1024 * 1024);
    cvt(Wk, wqkvb + 1024 * 1024, 1024 * 1024);
    cvt(Wv, wqkvb + 2 * 1024 * 1024, 1024 * 1024);
    cvt(Wo, wob, 1024 * 1024);
    cvt(W1, w1b, 4096 * 1024);
    cvt(W2, w2b, 1024 * 4096);

    // QKV = srcb @ Wqkv^T   (M=4096, N=3072, K=1024)
    gemm_bt<0><<<dim3(3072 / BN, 4096 / BM), 256, 0, stream>>>(srcb, wqkvb, nullptr, qkv, nullptr, 4096, 3072, 1024);
    // V transpose
    transpose_v<<<dim3(16, 64), 256, 0, stream>>>(qkv, vt);
    // attention (128 q rows per block)
    attn_kernel<<<dim3(8, 64), 256, 0, stream>>>(qkv, coords, vt, attno);
    // Wo partials: attno @ Wo^T, 2-way split-K (512 blocks = 2/CU)
    gemm_splitk<<<dim3(1024 / BN, 4096 / BM, 2), 256, 0, stream>>>(attno, wob, pbWo, 1024, 1024, 512);
    // x = LN(src + p0 + p1); xb = bf16(x)
    ln_sum_kernel<<<4096, 256, 0, stream>>>(src, pbWo, 2, nullptr, g1, be1, x, xb);
    // h1 = gelu(xb @ W1^T + b1)   -- 256^2 counted-vmcnt kernel, fast-GELU epilogue
    gemm256<2><<<dim3(4096 / 256, 4096 / 256), 512, 0, stream>>>(xb, w1b, nullptr, h1, b1, 4096, 4096, 1024);
    // FF2 partials: h1 @ W2^T, 4-way split-K (1024 blocks = 4/CU)
    gemm_splitk<<<dim3(1024 / BN, 4096 / BM, 4), 256, 0, stream>>>(h1, w2b, pbFF, 1024, 4096, 1024);
    // out = LN(x + p0+p1+p2+p3 + b2)
    ln_sum_kernel<<<4096, 256, 0, stream>>>(x, pbFF, 4, b2, g2, be2, out, nullptr);
}

// Round 10
// 339.283 us; speedup vs baseline: 1.1012x; 1.0319x over previous
//
#include <hip/hip_runtime.h>
#include <hip/hip_bf16.h>
#include <math.h>

#define DEV __device__ __forceinline__

typedef __attribute__((ext_vector_type(4))) float f32x4;
typedef __attribute__((ext_vector_type(16))) float f32x16;
typedef __attribute__((ext_vector_type(8))) short bf16x8;
typedef __attribute__((ext_vector_type(4))) unsigned short us4;

// ---------- scalar helpers ----------
DEV unsigned short f2bf(float f) {
    union { float f; unsigned u; } v; v.f = f;
    unsigned r = v.u + 0x7FFF + ((v.u >> 16) & 1);
    return (unsigned short)(r >> 16);
}

DEV float bf2f(unsigned short u) {
    union { unsigned u; float f; } v; v.u = (unsigned)u << 16; return v.f;
}

// tanh-form GELU (overflow-safe). ~1e-3 abs err, invisible under bf16 cast.
DEV float gelu_fast(float v) {
    float u = 0.7978845608f * v * (1.0f + 0.044715f * v * v);
    float e = __expf(-2.0f * fabsf(u));
    float th = (1.0f - e) / (1.0f + e);
    th = copysignf(th, u);
    return 0.5f * v * (1.0f + th);
}

DEV void async16(const void* g, void* l) {
    __builtin_amdgcn_global_load_lds(
        (const __attribute__((address_space(1))) void*)g,
        (__attribute__((address_space(3))) void*)l, 16, 0, 0);
}

// bijective XCD-aware remap (m204)
DEV int xcd_swizzle(int flat, int nwg) {
    int q = nwg >> 3, r8 = nwg & 7;
    int xcd = flat & 7, idx = flat >> 3;
    return (xcd < r8 ? xcd * (q + 1) : r8 * (q + 1) + (xcd - r8) * q) + idx;
}

// ---------- f32 -> bf16 convert ----------
__global__ void cvt_kernel(const float* __restrict__ in, unsigned short* __restrict__ out, int n4) {
    int i = blockIdx.x * blockDim.x + threadIdx.x;
    if (i >= n4) return;
    f32x4 v = ((const f32x4*)in)[i];
    us4 o;
    o.x = f2bf(v.x); o.y = f2bf(v.y); o.z = f2bf(v.z); o.w = f2bf(v.w);
    ((us4*)out)[i] = o;
}

// ---------- GEMM 128x128 (m97 structure): C[M,N] = A[M,K] * B[N,K]^T ----------
#define BM 128
#define BN 128
#define BKK 64

template<int EPI>
__global__ __launch_bounds__(256) void gemm_bt(
    const unsigned short* __restrict__ A,
    const unsigned short* __restrict__ B,
    float* __restrict__ Cf, unsigned short* __restrict__ Cb,
    const float* __restrict__ bias,
    int M, int N, int K)
{
    __shared__ unsigned short As[BM * BKK];
    __shared__ unsigned short Bs[BN * BKK];

    const int tid  = threadIdx.x;
    const int wid  = tid >> 6, lane = tid & 63;
    const int l15  = lane & 15, l16 = lane >> 4;
    const int wr   = wid >> 1, wc = wid & 1;

    const int nwg  = gridDim.x * gridDim.y;
    const int flat = xcd_swizzle(blockIdx.y * gridDim.x + blockIdx.x, nwg);
    const int row0 = (flat / gridDim.x) * BM;
    const int col0 = (flat % gridDim.x) * BN;

    f32x4 acc[4][4] = {};

    const int nkt = K / BKK;
    for (int kt = 0; kt < nkt; ++kt) {
        const int k0 = kt * BKK;
        __syncthreads();
#pragma unroll
        for (int i = 0; i < 4; ++i) {
            int c = i * 256 + tid;
            int row = c >> 3, slot = c & 7;
            int ks = (slot ^ (row & 7)) * 8;
            async16(A + (size_t)(row0 + row) * K + k0 + ks, (char*)As + c * 16);
            async16(B + (size_t)(col0 + row) * K + k0 + ks, (char*)Bs + c * 16);
        }
        __syncthreads();
#pragma unroll
        for (int kk = 0; kk < 2; ++kk) {
            bf16x8 af[4], bfr[4];
#pragma unroll
            for (int m = 0; m < 4; ++m) {
                int r = wr * 64 + m * 16 + l15;
                int slot = (kk * 4 + l16) ^ (r & 7);
                af[m] = *(const bf16x8*)((const char*)As + r * 128 + slot * 16);
            }
#pragma unroll
            for (int n = 0; n < 4; ++n) {
                int r = wc * 64 + n * 16 + l15;
                int slot = (kk * 4 + l16) ^ (r & 7);
                bfr[n] = *(const bf16x8*)((const char*)Bs + r * 128 + slot * 16);
            }
#pragma unroll
            for (int m = 0; m < 4; ++m)
#pragma unroll
                for (int n = 0; n < 4; ++n)
                    acc[m][n] = __builtin_amdgcn_mfma_f32_16x16x32_bf16(af[m], bfr[n], acc[m][n], 0, 0, 0);
        }
    }

#pragma unroll
    for (int m = 0; m < 4; ++m) {
        int grow = row0 + wr * 64 + m * 16 + l16 * 4;
#pragma unroll
        for (int n = 0; n < 4; ++n) {
            int gcol = col0 + wc * 64 + n * 16 + l15;
            float bv = (EPI >= 2) ? bias[gcol] : 0.f;
#pragma unroll
            for (int r = 0; r < 4; ++r) {
                float v = acc[m][n][r];
                size_t idx = (size_t)(grow + r) * N + gcol;
                if (EPI == 0) {
                    Cb[idx] = f2bf(v);
                } else if (EPI == 1) {
                    Cf[idx] = v;
                } else if (EPI == 2) {
                    Cb[idx] = f2bf(gelu_fast(v + bv));
                } else {
                    Cf[idx] = v + bv;
                }
            }
        }
    }
}

// ---------- split-K GEMM 128x128: P[s][M][N] = A[:, s*Klen:(s+1)*Klen] * B^T ----------
__global__ __launch_bounds__(256) void gemm_splitk(
    const unsigned short* __restrict__ A,
    const unsigned short* __restrict__ B,
    unsigned short* __restrict__ Pb,
    int N, int Kld, int Klen)
{
    __shared__ unsigned short As[BM * BKK];
    __shared__ unsigned short Bs[BN * BKK];

    const int tid  = threadIdx.x;
    const int wid  = tid >> 6, lane = tid & 63;
    const int l15  = lane & 15, l16 = lane >> 4;
    const int wr   = wid >> 1, wc = wid & 1;

    const int s = blockIdx.z;
    const unsigned short* Ab = A + (size_t)s * Klen;
    const unsigned short* Bb = B + (size_t)s * Klen;

    const int nwg  = gridDim.x * gridDim.y;
    const int flat = xcd_swizzle(blockIdx.y * gridDim.x + blockIdx.x, nwg);
    const int row0 = (flat / gridDim.x) * BM;
    const int col0 = (flat % gridDim.x) * BN;

    f32x4 acc[4][4] = {};

    const int nkt = Klen / BKK;
    for (int kt = 0; kt < nkt; ++kt) {
        const int k0 = kt * BKK;
        __syncthreads();
#pragma unroll
        for (int i = 0; i < 4; ++i) {
            int c = i * 256 + tid;
            int row = c >> 3, slot = c & 7;
            int ks = (slot ^ (row & 7)) * 8;
            async16(Ab + (size_t)(row0 + row) * Kld + k0 + ks, (char*)As + c * 16);
            async16(Bb + (size_t)(col0 + row) * Kld + k0 + ks, (char*)Bs + c * 16);
        }
        __syncthreads();
#pragma unroll
        for (int kk = 0; kk < 2; ++kk) {
            bf16x8 af[4], bfr[4];
#pragma unroll
            for (int m = 0; m < 4; ++m) {
                int r = wr * 64 + m * 16 + l15;
                int slot = (kk * 4 + l16) ^ (r & 7);
                af[m] = *(const bf16x8*)((const char*)As + r * 128 + slot * 16);
            }
#pragma unroll
            for (int n = 0; n < 4; ++n) {
                int r = wc * 64 + n * 16 + l15;
                int slot = (kk * 4 + l16) ^ (r & 7);
                bfr[n] = *(const bf16x8*)((const char*)Bs + r * 128 + slot * 16);
            }
#pragma unroll
            for (int m = 0; m < 4; ++m)
#pragma unroll
                for (int n = 0; n < 4; ++n)
                    acc[m][n] = __builtin_amdgcn_mfma_f32_16x16x32_bf16(af[m], bfr[n], acc[m][n], 0, 0, 0);
        }
    }

    unsigned short* P = Pb + (size_t)s * (size_t)(gridDim.y * BM) * N;
#pragma unroll
    for (int m = 0; m < 4; ++m) {
        int grow = row0 + wr * 64 + m * 16 + l16 * 4;
#pragma unroll
        for (int n = 0; n < 4; ++n) {
            int gcol = col0 + wc * 64 + n * 16 + l15;
#pragma unroll
            for (int r = 0; r < 4; ++r)
                P[(size_t)(grow + r) * N + gcol] = f2bf(acc[m][n][r]);
        }
    }
}

// ---------- GEMM 256x256, 8 waves, double-buffered, counted vmcnt ----------
template<int EPI>
__global__ __launch_bounds__(512, 2) void gemm256(
    const unsigned short* __restrict__ A,
    const unsigned short* __restrict__ B,
    float* __restrict__ Cf, unsigned short* __restrict__ Cb,
    const float* __restrict__ bias,
    int M, int N, int K)
{
    __shared__ unsigned short As[2][256 * 64];
    __shared__ unsigned short Bs[2][256 * 64];

    const int tid = threadIdx.x;
    const int wid = tid >> 6, lane = tid & 63;
    const int l15 = lane & 15, l16 = lane >> 4;
    const int wr = wid >> 2, wc = wid & 3;

    const int nwg  = gridDim.x * gridDim.y;
    const int flat = xcd_swizzle(blockIdx.y * gridDim.x + blockIdx.x, nwg);
    const int row0 = (flat / gridDim.x) * 256;
    const int col0 = (flat % gridDim.x) * 256;

    f32x4 acc[8][4] = {};

    auto stage = [&](int buf, int k0) {
#pragma unroll
        for (int i = 0; i < 4; ++i) {
            int c = i * 512 + tid;
            int row = c >> 3, slot = c & 7;
            int ks = (slot ^ (row & 7)) * 8;
            async16(A + (size_t)(row0 + row) * K + k0 + ks, (char*)As[buf] + c * 16);
            async16(B + (size_t)(col0 + row) * K + k0 + ks, (char*)Bs[buf] + c * 16);
        }
    };

    stage(0, 0);
    int cur = 0;
    const int nkt = K / 64;
    for (int kt = 0; kt < nkt; ++kt) {
        if (kt + 1 < nkt) {
            stage(cur ^ 1, (kt + 1) * 64);
            __builtin_amdgcn_sched_barrier(0);
            asm volatile("s_waitcnt vmcnt(8)" ::: "memory");
        } else {
            __builtin_amdgcn_sched_barrier(0);
            asm volatile("s_waitcnt vmcnt(0)" ::: "memory");
        }
        __builtin_amdgcn_sched_barrier(0);
        __builtin_amdgcn_s_barrier();
        __builtin_amdgcn_sched_barrier(0);
#pragma unroll
        for (int kk = 0; kk < 2; ++kk) {
            bf16x8 af[8], bfr[4];
#pragma unroll
            for (int m = 0; m < 8; ++m) {
                int r = wr * 128 + m * 16 + l15;
                int slot = (kk * 4 + l16) ^ (r & 7);
                af[m] = *(const bf16x8*)((const char*)As[cur] + r * 128 + slot * 16);
            }
#pragma unroll
            for (int n = 0; n < 4; ++n) {
                int r = wc * 64 + n * 16 + l15;
                int slot = (kk * 4 + l16) ^ (r & 7);
                bfr[n] = *(const bf16x8*)((const char*)Bs[cur] + r * 128 + slot * 16);
            }
            __builtin_amdgcn_s_setprio(1);
#pragma unroll
            for (int m = 0; m < 8; ++m)
#pragma unroll
                for (int n = 0; n < 4; ++n)
                    acc[m][n] = __builtin_amdgcn_mfma_f32_16x16x32_bf16(af[m], bfr[n], acc[m][n], 0, 0, 0);
            __builtin_amdgcn_s_setprio(0);
        }
        __builtin_amdgcn_sched_barrier(0);
        __builtin_amdgcn_s_barrier();
        __builtin_amdgcn_sched_barrier(0);
        cur ^= 1;
    }

#pragma unroll
    for (int m = 0; m < 8; ++m) {
        int grow = row0 + wr * 128 + m * 16 + l16 * 4;
#pragma unroll
        for (int n = 0; n < 4; ++n) {
            int gcol = col0 + wc * 64 + n * 16 + l15;
            float bv = (EPI >= 2) ? bias[gcol] : 0.f;
#pragma unroll
            for (int r = 0; r < 4; ++r) {
                float v = acc[m][n][r];
                size_t idx = (size_t)(grow + r) * N + gcol;
                if (EPI == 0) {
                    Cb[idx] = f2bf(v);
                } else if (EPI == 1) {
                    Cf[idx] = v;
                } else if (EPI == 2) {
                    Cb[idx] = f2bf(gelu_fast(v + bv));
                } else {
                    Cf[idx] = v + bv;
                }
            }
        }
    }
}

// ---------- V transpose: qkv V-part [B,N,H,64] -> vt [B,H,64,N] ----------
__global__ __launch_bounds__(256) void transpose_v(const unsigned short* __restrict__ qkv,
                                                   unsigned short* __restrict__ vt)
{
    __shared__ unsigned short t[64][72];
    const int n0 = blockIdx.x * 64;
    const int bh = blockIdx.y;
    const int b = bh >> 4, h = bh & 15;
    const int tid = threadIdx.x;
#pragma unroll
    for (int i = 0; i < 2; ++i) {
        int c = i * 256 + tid;
        int row = c >> 3, col0 = (c & 7) * 8;
        const unsigned short* src = qkv + (size_t)(b * 1024 + n0 + row) * 3072 + 2048 + h * 64 + col0;
        bf16x8 v = *(const bf16x8*)src;
#pragma unroll
        for (int j = 0; j < 8; ++j) t[row][col0 + j] = (unsigned short)v[j];
    }
    __syncthreads();
#pragma unroll
    for (int i = 0; i < 2; ++i) {
        int c = i * 256 + tid;
        int hd = c >> 3, col0 = (c & 7) * 8;
        bf16x8 v;
#pragma unroll
        for (int j = 0; j < 8; ++j) v[j] = (short)t[col0 + j][hd];
        *(bf16x8*)(vt + ((size_t)bh * 64 + hd) * 1024 + n0 + col0) = v;
    }
}

// ---------- fused attention: swapped QK^T, 32x32 MFMA, in-register softmax ----------
// Grid (64 bh, 8 qb): linear%8 = bh%8 -> all 8 q-blocks of a head share one XCD's L2.
// Static double buffers (Ks0/Ks1/Vs0/Vs1) -> compile-time LDS addressing.
__global__ __launch_bounds__(256) void attn_kernel(const unsigned short* __restrict__ qkv,
                                                   const int* __restrict__ coords,
                                                   const unsigned short* __restrict__ vt,
                                                   unsigned short* __restrict__ out)
{
    __shared__ unsigned short Ks0[64 * 64], Ks1[64 * 64];
    __shared__ unsigned short Vs0[64 * 64], Vs1[64 * 64];
    __shared__ float cF[1024 * 2];

    const int tid = threadIdx.x, wid = tid >> 6, lane = tid & 63;
    const int l31 = lane & 31, hi = lane >> 5;
    const int bh = blockIdx.x;                  // 0..63
    const int q0 = blockIdx.y * 128;            // 0..7 q-blocks
    const int b = bh >> 4, h = bh & 15;
    const float LOG2E = 1.4426950408889634f;
    const float slope2 = exp2f(-0.5f * (float)(h + 1)) * LOG2E;
    const float scale2 = 0.125f * LOG2E;

    const int c0 = tid,       r0c = c0 >> 3, ks0 = ((c0 & 7) ^ (r0c & 7)) * 8;
    const int c1 = 256 + tid, r1c = c1 >> 3, ks1 = ((c1 & 7) ^ (r1c & 7)) * 8;
    const unsigned short* kbase = qkv + (size_t)(b * 1024) * 3072 + 1024 + h * 64;
    const unsigned short* vbase = vt + (size_t)bh * 64 * 1024;

    {
        const int2* cp = (const int2*)coords + b * 1024;
#pragma unroll
        for (int i = 0; i < 4; ++i) {
            int kv = i * 256 + tid;
            int2 c = cp[kv];
            cF[kv * 2]     = slope2 * (float)c.x;
            cF[kv * 2 + 1] = slope2 * (float)c.y;
        }
    }

    const int qrow = q0 + wid * 32 + l31;
    bf16x8 qf[4];
    {
        const unsigned short* qp = qkv + (size_t)(b * 1024 + qrow) * 3072 + h * 64 + hi * 8;
        qf[0] = *(const bf16x8*)qp;
        qf[1] = *(const bf16x8*)(qp + 16);
        qf[2] = *(const bf16x8*)(qp + 32);
        qf[3] = *(const bf16x8*)(qp + 48);
    }
    float qxs, qys;
    {
        int2 qc = ((const int2*)coords)[b * 1024 + qrow];
        qxs = slope2 * (float)qc.x; qys = slope2 * (float)qc.y;
    }

    float mr = -1e30f, lr = 0.f;
    f32x16 o0 = (f32x16)0.f, o1 = (f32x16)0.f;

    auto stage = [&](unsigned short* KS, unsigned short* VS, int kv) {
        async16(kbase + (size_t)(kv + r0c) * 3072 + ks0, (char*)KS + c0 * 16);
        async16(kbase + (size_t)(kv + r1c) * 3072 + ks1, (char*)KS + c1 * 16);
        async16(vbase + (size_t)r0c * 1024 + kv + ks0, (char*)VS + c0 * 16);
        async16(vbase + (size_t)r1c * 1024 + kv + ks1, (char*)VS + c1 * 16);
    };

    auto do_tile = [&](const unsigned short* KS, const unsigned short* VS, int kv0) {
        // QK^T: S^T[kv][q], A = K rows, B = Q rows
        f32x16 s0 = (f32x16)0.f, s1 = (f32x16)0.f;
        __builtin_amdgcn_s_setprio(1);
#pragma unroll
        for (int c16 = 0; c16 < 4; ++c16) {
            int slot = ((c16 * 2 + hi) ^ (l31 & 7)) * 16;
            bf16x8 k0f = *(const bf16x8*)((const char*)KS + l31 * 128 + slot);
            bf16x8 k1f = *(const bf16x8*)((const char*)KS + (32 + l31) * 128 + slot);
            s0 = __builtin_amdgcn_mfma_f32_32x32x16_bf16(k0f, qf[c16], s0, 0, 0, 0);
            s1 = __builtin_amdgcn_mfma_f32_32x32x16_bf16(k1f, qf[c16], s1, 0, 0, 0);
        }
        __builtin_amdgcn_s_setprio(0);

        // bias in log2 domain
#pragma unroll
        for (int T = 0; T < 2; ++T) {
            f32x16& S = T ? s1 : s0;
#pragma unroll
            for (int u = 0; u < 4; ++u) {
                int kvb = kv0 + T * 32 + u * 8 + hi * 4;
                f32x4 ca = *(const f32x4*)&cF[kvb * 2];
                f32x4 cb = *(const f32x4*)&cF[kvb * 2 + 4];
                S[4*u+0] = S[4*u+0] * scale2 + (fabsf(qxs - ca.x) + fabsf(qys - ca.y));
                S[4*u+1] = S[4*u+1] * scale2 + (fabsf(qxs - ca.z) + fabsf(qys - ca.w));
                S[4*u+2] = S[4*u+2] * scale2 + (fabsf(qxs - cb.x) + fabsf(qys - cb.y));
                S[4*u+3] = S[4*u+3] * scale2 + (fabsf(qxs - cb.z) + fabsf(qys - cb.w));
            }
        }

        // tree max (depth 5, v_max3-fusable)
        float a[16];
#pragma unroll
        for (int i = 0; i < 16; ++i) a[i] = fmaxf(s0[i], s1[i]);
#pragma unroll
        for (int st = 8; st > 0; st >>= 1)
#pragma unroll
            for (int i = 0; i < st; ++i) a[i] = fmaxf(a[i], a[i + st]);
        float pm = fmaxf(a[0], __shfl_xor(a[0], 32, 64));

        if (__any(pm > mr + 8.0f)) {        // defer-max (T13)
            float mn = fmaxf(mr, pm);
            float corr = exp2f(mr - mn);
            mr = mn;
            lr *= corr;
#pragma unroll
            for (int i = 0; i < 16; ++i) { o0[i] *= corr; o1[i] *= corr; }
        }
        // exp + tree sum
        float bs[16];
#pragma unroll
        for (int i = 0; i < 16; ++i) {
            s0[i] = exp2f(s0[i] - mr);
            s1[i] = exp2f(s1[i] - mr);
            bs[i] = s0[i] + s1[i];
        }
#pragma unroll
        for (int st = 8; st > 0; st >>= 1)
#pragma unroll
            for (int i = 0; i < st; ++i) bs[i] += bs[i + st];
        lr += bs[0] + __shfl_xor(bs[0], 32, 64);

        // P -> bf16 B-fragments via cvt_pk + permlane32_swap (T12)
        bf16x8 pf[4];
#pragma unroll
        for (int c = 0; c < 4; ++c) {
            const f32x16& S = (c < 2) ? s0 : s1;
            const int e = (c & 1) * 8;
            unsigned x0, x1, y0, y1;
            asm("v_cvt_pk_bf16_f32 %0, %1, %2" : "=v"(x0) : "v"(S[e+0]), "v"(S[e+1]));
            asm("v_cvt_pk_bf16_f32 %0, %1, %2" : "=v"(x1) : "v"(S[e+2]), "v"(S[e+3]));
            asm("v_cvt_pk_bf16_f32 %0, %1, %2" : "=v"(y0) : "v"(S[e+4]), "v"(S[e+5]));
            asm("v_cvt_pk_bf16_f32 %0, %1, %2" : "=v"(y1) : "v"(S[e+6]), "v"(S[e+7]));
            asm("v_permlane32_swap_b32 %0, %1" : "+v"(x0), "+v"(y0));
            asm("v_permlane32_swap_b32 %0, %1" : "+v"(x1), "+v"(y1));
            union { unsigned u[4]; bf16x8 v; } pk_;
            pk_.u[0] = x0; pk_.u[1] = x1; pk_.u[2] = y0; pk_.u[3] = y1;
            pf[c] = pk_.v;
        }

        // PV: O^T += V^T * P
        __builtin_amdgcn_s_setprio(1);
#pragma unroll
        for (int c = 0; c < 4; ++c) {
            int slot = ((c * 2 + hi) ^ (l31 & 7)) * 16;
            bf16x8 v0 = *(const bf16x8*)((const char*)VS + l31 * 128 + slot);
            bf16x8 v1 = *(const bf16x8*)((const char*)VS + (32 + l31) * 128 + slot);
            o0 = __builtin_amdgcn_mfma_f32_32x32x16_bf16(v0, pf[c], o0, 0, 0, 0);
            o1 = __builtin_amdgcn_mfma_f32_32x32x16_bf16(v1, pf[c], o1, 0, 0, 0);
        }
        __builtin_amdgcn_s_setprio(0);
    };

    stage(Ks0, Vs0, 0);
    for (int it = 0; it < 8; ++it) {
        const int kv0 = it * 128;
        __syncthreads();                        // buf0 ready (vmcnt drained)
        stage(Ks1, Vs1, kv0 + 64);              // prefetch odd tile
        do_tile(Ks0, Vs0, kv0);
        __syncthreads();                        // buf1 ready; all done reading buf0
        if (it < 7) stage(Ks0, Vs0, kv0 + 128); // prefetch next even tile
        do_tile(Ks1, Vs1, kv0 + 64);
    }

    const float inv = 1.0f / lr;
    unsigned short* op = out + (size_t)(b * 1024 + qrow) * 1024 + h * 64;
#pragma unroll
    for (int Td = 0; Td < 2; ++Td) {
        const f32x16& O = Td ? o1 : o0;
#pragma unroll
        for (int u = 0; u < 4; ++u) {
            us4 w;
            w.x = f2bf(O[4*u+0] * inv);
            w.y = f2bf(O[4*u+1] * inv);
            w.z = f2bf(O[4*u+2] * inv);
            w.w = f2bf(O[4*u+3] * inv);
            *(us4*)(op + Td * 32 + u * 8 + hi * 4) = w;
        }
    }
}

// ---------- LayerNorm(a + sum P[s] + bias?) ----------
__global__ __launch_bounds__(256) void ln_sum_kernel(const float* __restrict__ a,
                                                     const unsigned short* __restrict__ pb, int nsplit,
                                                     const float* __restrict__ bias,
                                                     const float* __restrict__ g, const float* __restrict__ be,
                                                     float* __restrict__ xout, unsigned short* __restrict__ xb)
{
    __shared__ float red[2][4];
    const int row = blockIdx.x, tid = threadIdx.x;
    const int wid = tid >> 6, lane = tid & 63;
    const size_t idx = (size_t)row * 256 + tid;
    f32x4 v = ((const f32x4*)a)[idx];
    for (int s = 0; s < nsplit; ++s) {
        us4 p = ((const us4*)pb)[(size_t)s * 1048576 + idx];
        v.x += bf2f(p.x); v.y += bf2f(p.y); v.z += bf2f(p.z); v.w += bf2f(p.w);
    }
    if (bias) {
        f32x4 bv = ((const f32x4*)bias)[tid];
        v.x += bv.x; v.y += bv.y; v.z += bv.z; v.w += bv.w;
    }
    float s1 = v.x + v.y + v.z + v.w;
    float s2 = v.x * v.x + v.y * v.y + v.z * v.z + v.w * v.w;
#pragma unroll
    for (int off = 1; off < 64; off <<= 1) {
        s1 += __shfl_xor(s1, off, 64);
        s2 += __shfl_xor(s2, off, 64);
    }
    if (lane == 0) { red[0][wid] = s1; red[1][wid] = s2; }
    __syncthreads();
    s1 = red[0][0] + red[0][1] + red[0][2] + red[0][3];
    s2 = red[1][0] + red[1][1] + red[1][2] + red[1][3];
    float mu = s1 * (1.f / 1024.f);
    float var = s2 * (1.f / 1024.f) - mu * mu;
    float rstd = rsqrtf(var + 1e-5f);
    f32x4 gv = ((const f32x4*)g)[tid], bev = ((const f32x4*)be)[tid];
    f32x4 y = (v - mu) * rstd * gv + bev;
    if (xout) ((f32x4*)xout)[idx] = y;
    if (xb) {
        us4 ob;
        ob.x = f2bf(y.x); ob.y = f2bf(y.y); ob.z = f2bf(y.z); ob.w = f2bf(y.w);
        ((us4*)xb)[idx] = ob;
    }
}

// ---------- host ----------
extern "C" void kernel_launch(void* const* d_in, const int* in_sizes, int n_in,
                              void* d_out, int out_size, void* d_ws, size_t ws_size,
                              hipStream_t stream) {
    const float* src    = (const float*)d_in[0];
    const int*   coords = (const int*)d_in[1];
    const float* Wq     = (const float*)d_in[2];
    const float* Wk     = (const float*)d_in[3];
    const float* Wv     = (const float*)d_in[4];
    const float* Wo     = (const float*)d_in[5];
    const float* W1     = (const float*)d_in[6];
    const float* b1     = (const float*)d_in[7];
    const float* W2     = (const float*)d_in[8];
    const float* b2     = (const float*)d_in[9];
    const float* g1     = (const float*)d_in[10];
    const float* be1    = (const float*)d_in[11];
    const float* g2     = (const float*)d_in[12];
    const float* be2    = (const float*)d_in[13];
    float* out = (float*)d_out;

    char* ws = (char*)d_ws;
    size_t off = 0;
    auto alloc = [&](size_t bytes) { size_t o = off; off += (bytes + 255) & ~(size_t)255; return o; };

    const size_t BT = 4096;
    size_t qkv_off   = alloc(BT * 3072 * 2);
    size_t attno_off = alloc(BT * 1024 * 2);
    size_t vt_off    = alloc((size_t)64 * 64 * 1024 * 2);
    size_t x_off    = alloc(BT * 1024 * 4);
    size_t ffs_off  = alloc(BT * 1024 * 4);
    size_t srcb_off = alloc(BT * 1024 * 2);
    size_t wqkv_off = alloc((size_t)3072 * 1024 * 2);
    size_t wo_off   = alloc((size_t)1024 * 1024 * 2);
    size_t w1_off   = alloc((size_t)4096 * 1024 * 2);
    size_t w2_off   = alloc((size_t)1024 * 4096 * 2);
    (void)ws_size; (void)in_sizes; (void)n_in; (void)out_size;

    unsigned short* qkv   = (unsigned short*)(ws + qkv_off);
    unsigned short* attno = (unsigned short*)(ws + attno_off);
    unsigned short* vt    = (unsigned short*)(ws + vt_off);
    float*          x     = (float*)(ws + x_off);
    unsigned short* pbWo  = (unsigned short*)(ws + ffs_off);
    unsigned short* pbFF  = (unsigned short*)(ws + ffs_off);
    unsigned short* srcb  = (unsigned short*)(ws + srcb_off);
    unsigned short* xb    = (unsigned short*)(ws + srcb_off);
    unsigned short* wqkvb = (unsigned short*)(ws + wqkv_off);
    unsigned short* wob   = (unsigned short*)(ws + wo_off);
    unsigned short* w1b   = (unsigned short*)(ws + w1_off);
    unsigned short* w2b   = (unsigned short*)(ws + w2_off);
    unsigned short* h1    = (unsigned short*)(ws + qkv_off);

    auto cvt = [&](const float* in, unsigned short* o, size_t n) {
        int n4 = (int)(n / 4);
        cvt_kernel<<<(n4 + 255) / 256, 256, 0, stream>>>(in, o, n4);
    };
    cvt(src, srcb, BT * 1024);
    cvt(Wq, wqkvb, 1024 * 1024);
    cvt(Wk, wqkvb + 1024 * 1024, 1024 * 1024);
    cvt(Wv, wqkvb + 2 * 1024 * 1024, 1024 * 1024);
    cvt(Wo, wob, 1024 * 1024);
    cvt(W1, w1b, 4096 * 1024);
    cvt(W2, w2b, 1024 * 4096);

    // QKV = srcb @ Wqkv^T
    gemm_bt<0><<<dim3(3072 / BN, 4096 / BM), 256, 0, stream>>>(srcb, wqkvb, nullptr, qkv, nullptr, 4096, 3072, 1024);
    // V transpose
    transpose_v<<<dim3(16, 64), 256, 0, stream>>>(qkv, vt);
    // attention: grid (bh, qb) so a head's q-blocks share an XCD
    attn_kernel<<<dim3(64, 8), 256, 0, stream>>>(qkv, coords, vt, attno);
    // Wo partials: 2-way split-K
    gemm_splitk<<<dim3(1024 / BN, 4096 / BM, 2), 256, 0, stream>>>(attno, wob, pbWo, 1024, 1024, 512);
    // x = LN(src + p0 + p1); xb = bf16(x)
    ln_sum_kernel<<<4096, 256, 0, stream>>>(src, pbWo, 2, nullptr, g1, be1, x, xb);
    // h1 = gelu(xb @ W1^T + b1)
    gemm256<2><<<dim3(4096 / 256, 4096 / 256), 512, 0, stream>>>(xb, w1b, nullptr, h1, b1, 4096, 4096, 1024);
    // FF2 partials: 4-way split-K
    gemm_splitk<<<dim3(1024 / BN, 4096 / BM, 4), 256, 0, stream>>>(h1, w2b, pbFF, 1024, 4096, 1024);
    // out = LN(x + sum p + b2)
    ln_sum_kernel<<<4096, 256, 0, stream>>>(x, pbFF, 4, b2, g2, be2, out, nullptr);
}